// Round 25
// baseline (43.572 us; speedup 1.0000x reference)
//
#include <hip/hip_runtime.h>

// AttentionConvFull: grouped 1x1 QKV + 5x5 per-channel local attention, FUSED.
// B=4, H=W=56, C=OC=256, G=8, Cg=32, K=5, pad=2.
//
// R25 = R24 (MFMA projection, 40.2us) with the REAL spill source + LDS
// ceiling addressed:
//  1) staging loop unroll 9 -> 3: the fully-unrolled 9 global loads +
//     addresses were the likely ~128-reg peak (R24's B/D split didn't move
//     VGPR, so the peak wasn't the MFMA pass).
//  2) wTs LDS buffer ELIMINATED: B-frags load directly from global w
//     (f32->f16 cvt in reg; L1/L2-hot - 196 blocks share each group's w).
//     LDS 47.1 -> 38.9 KB => 4 blocks/CU (was 3).
//  3) single MFMA pass again (6 B-frags + 6 D = ~52 regs; split was useless).
//  4) kvs/qs rows padded to 34 words: write conflicts 4-way -> 2-way (free),
//     reads conflict-free. (R24 conflict count = only 2.4% of cycles - minor.)
//
// MFMA geometry (m89-verified): D[144x96] = A[144x32] x B[32x96];
// A frag: lane(row=lw&15, k=(lw>>4)*8+j); B frag: B[k][col]=w_f16[col][k];
// D: col=lane&15, row=(lane>>4)*4+reg. 16x16x32_f16, 54 MFMA/block.
//
// Register law (R1-R24): cap=256/N; spill signature: VGPR==cap AND
// WRITE >> 12.5MB. Precision: f16 proj + bf16 k,v/rel = 2.34e-2 measured;
// threshold 5.69e-2.

constexpr int TB = 4, TH = 56, TW = 56, TC = 256;
constexpr int G  = 8, CG = 32, PAD = 2;
constexpr int TILE = 8;
constexpr int HT = TILE + 2 * PAD;   // 12
constexpr int NT = TH / TILE;        // 7
constexpr int NPIX_HALO = HT * HT;   // 144
constexpr int XP = 40;               // padded row (halves) for xs16
constexpr int KP = 34;               // padded row (words) for kvs/qs
constexpr float LOG2E = 1.44269504088896340736f;

typedef __fp16 half2_t __attribute__((ext_vector_type(2)));
typedef __fp16 half8   __attribute__((ext_vector_type(8)));
typedef float  f32x4   __attribute__((ext_vector_type(4)));

__device__ __forceinline__ unsigned h2u(half2_t h) {
    union { half2_t h; unsigned u; } cv; cv.h = h; return cv.u;
}
__device__ __forceinline__ unsigned packbf(float k, float v) {
    return ((__float_as_uint(k) + 0x8000u) >> 16) |
           ((__float_as_uint(v) + 0x8000u) & 0xffff0000u);
}
// B-fragment for col (=oc within group), k-range [ko,ko+8): w row segment.
__device__ __forceinline__ half8 load_w_frag(const float* __restrict__ w,
                                             int row, int ko) {
    const float4 a = *(const float4*)(w + (size_t)row * CG + ko);
    const float4 b = *(const float4*)(w + (size_t)row * CG + ko + 4);
    const half2_t h0 = __builtin_amdgcn_cvt_pkrtz(a.x, a.y);
    const half2_t h1 = __builtin_amdgcn_cvt_pkrtz(a.z, a.w);
    const half2_t h2 = __builtin_amdgcn_cvt_pkrtz(b.x, b.y);
    const half2_t h3 = __builtin_amdgcn_cvt_pkrtz(b.z, b.w);
    half8 h;
    h[0]=h0[0]; h[1]=h0[1]; h[2]=h1[0]; h[3]=h1[1];
    h[4]=h2[0]; h[5]=h2[1]; h[6]=h3[0]; h[7]=h3[1];
    return h;
}

__global__ __launch_bounds__(256, 2)
void fused_attn_conv_kernel(const float* __restrict__ x,
                            const float* __restrict__ wq,
                            const float* __restrict__ wk,
                            const float* __restrict__ wv,
                            const float* __restrict__ rel,
                            const float* __restrict__ qemb,
                            float* __restrict__ out) {
    __shared__ __align__(16) __fp16 xs16[NPIX_HALO][XP];  // 11.25 KB
    __shared__ unsigned kvs[NPIX_HALO][KP];               // 19.1 KB
    __shared__ float    qs[TILE * TILE][KP];              // 8.5 KB

    const int bid  = blockIdx.x;
    const int g    = bid & 7;
    const int tile = bid >> 3;
    const int tj   = tile % NT;
    const int ti   = (tile / NT) % NT;
    const int b    = tile / (NT * NT);

    const int t  = threadIdx.x;
    const int c  = t & 31;
    const int p0 = t >> 5;

    const int oc = g * CG + c;           // global out-channel (phase C)
    const int h0 = ti * TILE - PAD, w0 = tj * TILE - PAD;

    // ---- Stage x halo -> xs16 (f16 pairs; 2304 u32 = 9/thread, coalesced).
    //      unroll 3: cap in-flight loads (R24's unroll-9 was the VGPR peak).
    unsigned (*xsu)[XP / 2] = (unsigned(*)[XP / 2])xs16;
#pragma unroll 3
    for (int r = 0; r < 9; ++r) {
        const int f  = t + r * 256;          // 0..2303
        const int px = f >> 4, pr = f & 15;  // 16 channel-pairs per pixel
        const int hi = px / HT, hj = px % HT;
        const int gh = h0 + hi, gw = w0 + hj;
        unsigned val = 0u;
        if (gh >= 0 && gh < TH && gw >= 0 && gw < TW) {
            const float2 xv = *(const float2*)(x + (((size_t)b * TH + gh) * TW + gw) * TC
                                                 + g * CG + pr * 2);
            val = h2u(__builtin_amdgcn_cvt_pkrtz(xv.x, xv.y));
        }
        xsu[px][pr] = val;
    }

    __syncthreads();   // stage -> MFMA

    // ---- MFMA projection: D[144x96] = A[144x32] x B[32x96], single pass.
    {
        const int wvid = t >> 6, lw = t & 63;
        const int lcol = lw & 15;
        const int lko  = (lw >> 4) * 8;
        const half8 bq0 = load_w_frag(wq, g * CG + lcol,      lko);
        const half8 bq1 = load_w_frag(wq, g * CG + lcol + 16, lko);
        const half8 bk0 = load_w_frag(wk, g * CG + lcol,      lko);
        const half8 bk1 = load_w_frag(wk, g * CG + lcol + 16, lko);
        const half8 bv0 = load_w_frag(wv, g * CG + lcol,      lko);
        const half8 bv1 = load_w_frag(wv, g * CG + lcol + 16, lko);
        const float qeL = qemb[g * CG + lcol];
        const float qeH = qemb[g * CG + lcol + 16];
        const f32x4 z4 = {0.f, 0.f, 0.f, 0.f};

#pragma unroll 1
        for (int mt = wvid; mt < 9; mt += 4) {        // waves: 3/2/2/2 M-tiles
            const half8 a = *(const half8*)&xs16[mt * 16 + lcol][lko];
            const f32x4 dq0 = __builtin_amdgcn_mfma_f32_16x16x32_f16(a, bq0, z4, 0, 0, 0);
            const f32x4 dq1 = __builtin_amdgcn_mfma_f32_16x16x32_f16(a, bq1, z4, 0, 0, 0);
            const f32x4 dk0 = __builtin_amdgcn_mfma_f32_16x16x32_f16(a, bk0, z4, 0, 0, 0);
            const f32x4 dk1 = __builtin_amdgcn_mfma_f32_16x16x32_f16(a, bk1, z4, 0, 0, 0);
            const f32x4 dv0 = __builtin_amdgcn_mfma_f32_16x16x32_f16(a, bv0, z4, 0, 0, 0);
            const f32x4 dv1 = __builtin_amdgcn_mfma_f32_16x16x32_f16(a, bv1, z4, 0, 0, 0);
            const int prow = mt * 16 + ((lw >> 4) << 2);
#pragma unroll
            for (int j = 0; j < 4; ++j) {
                const int px = prow + j;
                kvs[px][lcol]      = packbf(dk0[j], dv0[j]);
                kvs[px][lcol + 16] = packbf(dk1[j], dv1[j]);
                const int hi2 = px / HT, hj2 = px % HT;
                if (hi2 >= PAD && hi2 < PAD + TILE && hj2 >= PAD && hj2 < PAD + TILE) {
                    const int qp = (hi2 - PAD) * TILE + (hj2 - PAD);
                    qs[qp][lcol]      = (dq0[j] + qeL) * LOG2E;
                    qs[qp][lcol + 16] = (dq1[j] + qeH) * LOG2E;
                }
            }
        }
    }

    // rel row -> 13 packed bf16 pairs (even idx = low half, odd = high half)
    unsigned relp[13];
    {
        const float* rp = rel + (size_t)oc * 25;
#pragma unroll
        for (int i = 0; i < 12; ++i) {
            const unsigned lo = __float_as_uint(rp[2 * i])     + 0x8000u;
            const unsigned hi = __float_as_uint(rp[2 * i + 1]) + 0x8000u;
            relp[i] = (lo >> 16) | (hi & 0xffff0000u);
        }
        relp[12] = (__float_as_uint(rp[24]) + 0x8000u) >> 16;
    }

    __syncthreads();   // MFMA -> phase C

    // q (already *log2e) for this thread's 8 column pixels
    float qreg[8];
#pragma unroll
    for (int ii = 0; ii < 8; ++ii) qreg[ii] = qs[ii * TILE + p0][c];

    // ---- Phase C: monolithic row-streaming attention (champion structure).
    float s_[8], a_[8];
#pragma unroll
    for (int ii = 0; ii < 8; ++ii) { s_[ii] = 0.f; a_[ii] = 0.f; }

#pragma unroll
    for (int h = 0; h < HT; ++h) {
        float kr[5], vr[5];
#pragma unroll
        for (int j = 0; j < 5; ++j) {
            const unsigned u = kvs[h * HT + p0 + j][c];
            kr[j] = __uint_as_float(u << 16);          // bf16 k -> f32
            vr[j] = __uint_as_float(u & 0xffff0000u);  // bf16 v -> f32
        }
#pragma unroll
        for (int ii = 0; ii < 8; ++ii) {
            const int di = h - ii;               // compile-time after unroll
            if (di >= 0 && di < 5) {
                const float qv = qreg[ii];
#pragma unroll
                for (int j = 0; j < 5; ++j) {
                    const int idx = di * 5 + j;  // compile-time
                    const unsigned ru = relp[idx >> 1];
                    const float rl = __uint_as_float((idx & 1) ? (ru & 0xffff0000u)
                                                               : (ru << 16));
                    const float e = __builtin_amdgcn_exp2f(qv * (kr[j] + rl));
                    s_[ii] += e;
                    a_[ii] = fmaf(e, vr[j], a_[ii]);
                }
            }
        }
    }

#pragma unroll
    for (int ii = 0; ii < 8; ++ii) {
        const int gh = ti * TILE + ii, gw = tj * TILE + p0;
        out[(((size_t)b * TH + gh) * TW + gw) * TC + g * CG + c] =
            a_[ii] * __builtin_amdgcn_rcpf(s_[ii]);
    }
}

extern "C" void kernel_launch(void* const* d_in, const int* in_sizes, int n_in,
                              void* d_out, int out_size, void* d_ws, size_t ws_size,
                              hipStream_t stream) {
    const float* x    = (const float*)d_in[0];
    const float* wq   = (const float*)d_in[1];
    const float* wk   = (const float*)d_in[2];
    const float* wv   = (const float*)d_in[3];
    const float* rel  = (const float*)d_in[4];
    const float* qemb = (const float*)d_in[5];
    float* out = (float*)d_out;

    const int nblocks = TB * NT * NT * G;   // 4*7*7*8 = 1568
    hipLaunchKernelGGL(fused_attn_conv_kernel, dim3(nblocks), dim3(256), 0, stream,
                       x, wq, wk, wv, rel, qemb, out);
}